// Round 1
// baseline (334.606 us; speedup 1.0000x reference)
//
#include <hip/hip_runtime.h>
#include <hip/hip_bf16.h>
#include <cstdint>
#include <cstddef>

// Problem constants (fixed by the reference)
//   B=8, L=1024, D_MODEL=1024, NUM_HEADS=16, QUERY_GROUPS=4, HEAD_DIM=64
//   QKV_OUT = 1536, H_patch=W_patch=32

typedef __bf16 bf16x8 __attribute__((ext_vector_type(8)));
typedef __bf16 bf16x4 __attribute__((ext_vector_type(4)));
typedef float floatx4 __attribute__((ext_vector_type(4)));

typedef unsigned int u32_g __attribute__((address_space(1)));
typedef unsigned int u32_l __attribute__((address_space(3)));

// async global->LDS, 16B per lane; LDS dest = wave-uniform base + lane*16
__device__ __forceinline__ void gl_lds16(const void* g, void* l) {
  __builtin_amdgcn_global_load_lds((const u32_g*)g, (u32_l*)l, 16, 0, 0);
}

// ---------------- fp32 -> bf16 convert ----------------
__global__ __launch_bounds__(256) void cvt_bf16(const float* __restrict__ in,
                                                __bf16* __restrict__ out, int n4) {
  int i = blockIdx.x * 256 + threadIdx.x;
  if (i >= n4) return;
  float4 v = ((const float4*)in)[i];
  bf16x4 o = {(__bf16)v.x, (__bf16)v.y, (__bf16)v.z, (__bf16)v.w};
  ((bf16x4*)out)[i] = o;
}

// ---------------- NT GEMM: C[M,N] = A[M,K] * B[N,K]^T ----------------
// A,B bf16 row-major K-contiguous. Output fp32 (Cf) or bf16 (Cb).
// 128x128 tile, BK=64, 256 threads = 4 waves in 2x2, each wave 64x64 via
// 4x4 tiles of v_mfma_f32_16x16x32_bf16. m97-style global_load_lds staging.
__global__ __launch_bounds__(256, 2)
void gemm_bt(const __bf16* __restrict__ A, const __bf16* __restrict__ B,
             float* __restrict__ Cf, __bf16* __restrict__ Cb,
             int M, int N, int K) {
  __shared__ __align__(16) __bf16 sA[128 * 64];
  __shared__ __align__(16) __bf16 sB[128 * 64];
  const int tid = threadIdx.x;
  const int wave = tid >> 6, lane = tid & 63;
  const int ntiles = N >> 7;
  const int bm = blockIdx.x / ntiles, bn = blockIdx.x % ntiles;
  const int wm = wave & 1, wn = wave >> 1;
  const int rowA0 = bm << 7, rowB0 = bn << 7;
  const int lr = lane >> 3;        // row within 8-row chunk
  const int lc = (lane & 7) * 8;   // col element (16B per lane)

  floatx4 acc[4][4] = {};

  for (int k0 = 0; k0 < K; k0 += 64) {
    __syncthreads();
    for (int j = 0; j < 4; ++j) {
      int c = wave * 4 + j;  // chunk 0..15, 8 rows each
      gl_lds16(A + (size_t)(rowA0 + c * 8 + lr) * K + k0 + lc, sA + c * 512);
      gl_lds16(B + (size_t)(rowB0 + c * 8 + lr) * K + k0 + lc, sB + c * 512);
    }
    __syncthreads();
    for (int kb = 0; kb < 64; kb += 32) {
      const int ko = kb + (lane >> 4) * 8;
      bf16x8 af[4], bfv[4];
      for (int t = 0; t < 4; ++t) {
        af[t]  = *(const bf16x8*)(sA + (wm * 64 + t * 16 + (lane & 15)) * 64 + ko);
        bfv[t] = *(const bf16x8*)(sB + (wn * 64 + t * 16 + (lane & 15)) * 64 + ko);
      }
      for (int mt = 0; mt < 4; ++mt)
        for (int nt = 0; nt < 4; ++nt)
          acc[mt][nt] = __builtin_amdgcn_mfma_f32_16x16x32_bf16(af[mt], bfv[nt],
                                                                acc[mt][nt], 0, 0, 0);
    }
  }
  // epilogue: C/D layout col=lane&15, row=(lane>>4)*4+reg (m89-verified)
  for (int mt = 0; mt < 4; ++mt)
    for (int nt = 0; nt < 4; ++nt)
      for (int r = 0; r < 4; ++r) {
        int row = rowA0 + wm * 64 + mt * 16 + (lane >> 4) * 4 + r;
        int col = rowB0 + wn * 64 + nt * 16 + (lane & 15);
        if (Cf) Cf[(size_t)row * N + col] = acc[mt][nt][r];
        else    Cb[(size_t)row * N + col] = (__bf16)acc[mt][nt][r];
      }
}

// ---------------- qk-norm + RoPE2D + layout split ----------------
// One wave per (row, head-chunk). row = b*1024 + l. 24 chunks/row:
// 0..15 q heads, 16..19 k groups, 20..23 v groups.
// Q[b][h][l][d], K[b][g][l][d], Vt[b][g][d][l] all bf16.
__global__ __launch_bounds__(256)
void normrope(const __bf16* __restrict__ qkv, __bf16* __restrict__ Q,
              __bf16* __restrict__ K, __bf16* __restrict__ Vt,
              const int* __restrict__ Wp) {
  const int unit = blockIdx.x * 4 + (threadIdx.x >> 6);
  const int lane = threadIdx.x & 63;
  const int row = unit / 24, hh = unit % 24;
  const int b = row >> 10, l = row & 1023;

  const __bf16* src;
  if (hh < 16)      src = qkv + (size_t)row * 1536 + hh * 64;
  else if (hh < 20) src = qkv + (size_t)row * 1536 + 1024 + (hh - 16) * 64;
  else              src = qkv + (size_t)row * 1536 + 1280 + (hh - 20) * 64;
  float t = (float)src[lane];

  if (hh < 20) {
    // L2 norm over the 64-dim head
    float ss = t * t;
    for (int m = 1; m < 64; m <<= 1) ss += __shfl_xor(ss, m);
    t = t / (sqrtf(ss) + 1e-10f);
    // RoPE2D: out[i]   = x1[i]*cos - x2[i]*sin  (i<32)
    //         out[32+i]= x1[i]*sin + x2[i]*cos, x1=t[2i], x2=t[2i+1]
    const int W = Wp[0];
    const int ph = l / W, pw = l % W;
    const int i = lane & 31;
    float x1 = __shfl(t, 2 * i);
    float x2 = __shfl(t, 2 * i + 1);
    float invf = exp2f(-(float)i * (0.03125f) * 13.287712379549449f); // log2(1e4)
    float f = (float)(ph + pw) * invf;
    float c = cosf(f), s = sinf(f);
    t = (lane < 32) ? (x1 * c - x2 * s) : (x1 * s + x2 * c);
  }

  if (hh < 16)
    Q[(((size_t)b * 16 + hh) * 1024 + l) * 64 + lane] = (__bf16)t;
  else if (hh < 20)
    K[(((size_t)b * 4 + (hh - 16)) * 1024 + l) * 64 + lane] = (__bf16)t;
  else
    Vt[(((size_t)b * 4 + (hh - 20)) * 64 + lane) * 1024 + l] = (__bf16)t;
}

// ---------------- flash attention ----------------
// Grid: (qt, h, b) linear, 8*16*8 = 1024 blocks. BLOCK_M=128 q rows,
// BLOCK_N=64 keys/iter, D=64. 4 waves, each owns 32 q rows.
__global__ __launch_bounds__(256, 2)
void flash(const __bf16* __restrict__ Q, const __bf16* __restrict__ K,
           const __bf16* __restrict__ Vt, __bf16* __restrict__ Oout) {
  __shared__ __align__(16) __bf16 sQ[128 * 64];
  __shared__ __align__(16) __bf16 sK[64 * 64];
  __shared__ __align__(16) __bf16 sV[64 * 64];  // [dim][key]
  __shared__ __align__(16) __bf16 sP[128 * 64];
  const int tid = threadIdx.x, wave = tid >> 6, lane = tid & 63;
  const int bid = blockIdx.x;
  const int qt = bid & 7, h = (bid >> 3) & 15, b = bid >> 7;
  const int g = h >> 2;
  const __bf16* Qb = Q + (((size_t)b * 16 + h) * 1024 + qt * 128) * 64;
  const __bf16* Kb = K + ((size_t)b * 4 + g) * 1024 * 64;
  const __bf16* Vb = Vt + ((size_t)b * 4 + g) * 64 * 1024;

  // Q tile is a contiguous 16KB block
  for (int j = 0; j < 4; ++j) {
    int c = wave * 4 + j;
    gl_lds16(Qb + c * 512 + lane * 8, sQ + c * 512);
  }

  float m_i[2][4], l_i[2][4];
  floatx4 accO[2][4] = {};
  for (int mt = 0; mt < 2; ++mt)
    for (int r = 0; r < 4; ++r) { m_i[mt][r] = -INFINITY; l_i[mt][r] = 0.f; }

  const float scale = 0.125f;  // 1/sqrt(64)

  for (int kt = 0; kt < 16; ++kt) {
    __syncthreads();  // prev iter's LDS reads done (and Q drained on iter 0)
    if (wave < 2) {   // K tile: 64x64 contiguous
      for (int j = 0; j < 4; ++j) {
        int c = wave * 4 + j;
        gl_lds16(Kb + (size_t)kt * 4096 + c * 512 + lane * 8, sK + c * 512);
      }
    } else {          // Vt tile: rows d, row stride 1024
      for (int j = 0; j < 4; ++j) {
        int c = (wave - 2) * 4 + j;
        gl_lds16(Vb + (size_t)(c * 8 + (lane >> 3)) * 1024 + kt * 64 + (lane & 7) * 8,
                 sV + c * 512);
      }
    }
    __syncthreads();

    // S = Q K^T for this wave's 32 rows x 64 keys
    floatx4 accS[2][4] = {};
    for (int kb = 0; kb < 64; kb += 32) {
      const int ko = kb + (lane >> 4) * 8;
      bf16x8 qf[2], kf[4];
      for (int mt = 0; mt < 2; ++mt)
        qf[mt] = *(const bf16x8*)(sQ + (wave * 32 + mt * 16 + (lane & 15)) * 64 + ko);
      for (int nt = 0; nt < 4; ++nt)
        kf[nt] = *(const bf16x8*)(sK + (nt * 16 + (lane & 15)) * 64 + ko);
      for (int mt = 0; mt < 2; ++mt)
        for (int nt = 0; nt < 4; ++nt)
          accS[mt][nt] = __builtin_amdgcn_mfma_f32_16x16x32_bf16(qf[mt], kf[nt],
                                                                 accS[mt][nt], 0, 0, 0);
    }

    // online softmax; rows live at (lane>>4)*4+r per m-tile
    for (int mt = 0; mt < 2; ++mt) {
      for (int r = 0; r < 4; ++r) {
        float mx = fmaxf(fmaxf(accS[mt][0][r], accS[mt][1][r]),
                         fmaxf(accS[mt][2][r], accS[mt][3][r])) * scale;
        for (int msk = 1; msk < 16; msk <<= 1) mx = fmaxf(mx, __shfl_xor(mx, msk));
        float mnew = fmaxf(m_i[mt][r], mx);
        float alpha = __expf(m_i[mt][r] - mnew);
        float sum = 0.f;
        for (int nt = 0; nt < 4; ++nt) {
          float p = __expf(accS[mt][nt][r] * scale - mnew);
          sum += p;
          // P in A-layout staging row-major (this wave's own rows only)
          sP[(wave * 32 + mt * 16 + (lane >> 4) * 4 + r) * 64 + nt * 16 + (lane & 15)] =
              (__bf16)p;
        }
        for (int msk = 1; msk < 16; msk <<= 1) sum += __shfl_xor(sum, msk);
        l_i[mt][r] = l_i[mt][r] * alpha + sum;
        m_i[mt][r] = mnew;
        for (int nt = 0; nt < 4; ++nt) accO[mt][nt][r] *= alpha;
      }
    }

    // O += P * V   (A = P from LDS, B = Vt[dim][key])
    for (int kb = 0; kb < 64; kb += 32) {
      const int ko = kb + (lane >> 4) * 8;
      bf16x8 pf[2], vf[4];
      for (int mt = 0; mt < 2; ++mt)
        pf[mt] = *(const bf16x8*)(sP + (wave * 32 + mt * 16 + (lane & 15)) * 64 + ko);
      for (int nt = 0; nt < 4; ++nt)
        vf[nt] = *(const bf16x8*)(sV + (nt * 16 + (lane & 15)) * 64 + ko);
      for (int mt = 0; mt < 2; ++mt)
        for (int nt = 0; nt < 4; ++nt)
          accO[mt][nt] = __builtin_amdgcn_mfma_f32_16x16x32_bf16(pf[mt], vf[nt],
                                                                 accO[mt][nt], 0, 0, 0);
    }
  }

  // epilogue: normalize and write attn[b][l][h*64+d]
  for (int mt = 0; mt < 2; ++mt)
    for (int r = 0; r < 4; ++r) {
      float inv = 1.f / l_i[mt][r];
      int row = qt * 128 + wave * 32 + mt * 16 + (lane >> 4) * 4 + r;
      for (int nt = 0; nt < 4; ++nt) {
        int col = nt * 16 + (lane & 15);
        Oout[((size_t)b * 1024 + row) * 1024 + h * 64 + col] =
            (__bf16)(accO[mt][nt][r] * inv);
      }
    }
}

extern "C" void kernel_launch(void* const* d_in, const int* in_sizes, int n_in,
                              void* d_out, int out_size, void* d_ws, size_t ws_size,
                              hipStream_t stream) {
  const float* x     = (const float*)d_in[0];
  const float* w_qkv = (const float*)d_in[1];
  const float* w_o   = (const float*)d_in[2];
  const int*   Wp    = (const int*)d_in[4];
  float* out = (float*)d_out;
  char* ws = (char*)d_ws;

  // workspace layout (attn aliases xb: xb dead after gemm1)
  __bf16* xb    = (__bf16*)(ws + 0);          // 16 MiB
  __bf16* attn  = (__bf16*)(ws + 0);          // 16 MiB (alias)
  __bf16* wqkvb = (__bf16*)(ws + 16777216);   // 3 MiB
  __bf16* wob   = (__bf16*)(ws + 19922944);   // 2 MiB
  __bf16* qkvb  = (__bf16*)(ws + 22020096);   // 24 MiB
  __bf16* Qb    = (__bf16*)(ws + 47185920);   // 16 MiB
  __bf16* Kb    = (__bf16*)(ws + 63963136);   // 4 MiB
  __bf16* Vtb   = (__bf16*)(ws + 68157440);   // 4 MiB  (total 72.4 MiB)

  cvt_bf16<<<8192, 256, 0, stream>>>(x, xb, 2097152);
  cvt_bf16<<<1536, 256, 0, stream>>>(w_qkv, wqkvb, 393216);
  cvt_bf16<<<1024, 256, 0, stream>>>(w_o, wob, 262144);

  // qkv = x @ w_qkv^T : M=8192 N=1536 K=1024 -> bf16
  gemm_bt<<<64 * 12, 256, 0, stream>>>(xb, wqkvb, nullptr, qkvb, 8192, 1536, 1024);

  // qk-norm + rope + split/transpose
  normrope<<<49152, 256, 0, stream>>>(qkvb, Qb, Kb, Vtb, Wp);

  // fused attention
  flash<<<1024, 256, 0, stream>>>(Qb, Kb, Vtb, attn);

  // out = attn @ w_o^T : M=8192 N=1024 K=1024 -> fp32 d_out
  gemm_bt<<<64 * 8, 256, 0, stream>>>(attn, wob, out, nullptr, 8192, 1024, 1024);
}

// Round 3
// 274.735 us; speedup vs baseline: 1.2179x; 1.2179x over previous
//
#include <hip/hip_runtime.h>
#include <hip/hip_bf16.h>
#include <cstdint>
#include <cstddef>

// B=8, L=1024, D=1024, NUM_HEADS=16, QUERY_GROUPS=4, HEAD_DIM=64, QKV_OUT=1536

typedef __bf16 bf16x8 __attribute__((ext_vector_type(8)));
typedef __bf16 bf16x4 __attribute__((ext_vector_type(4)));
typedef float floatx4 __attribute__((ext_vector_type(4)));

typedef unsigned int u32_g __attribute__((address_space(1)));
typedef unsigned int u32_l __attribute__((address_space(3)));

__device__ __forceinline__ void gl_lds16(const void* g, void* l) {
  __builtin_amdgcn_global_load_lds((const u32_g*)g, (u32_l*)l, 16, 0, 0);
}

// chunk-padded LDS staging: each 1024B chunk (8 rows x 64 bf16) + 16B pad.
// CH elements per chunk slot; row r, col k -> (r>>3)*CH + (r&7)*64 + k.
constexpr int CH = 520;
__device__ __forceinline__ int pidx(int r, int k) {
  return (r >> 3) * CH + (r & 7) * 64 + k;
}

// ---------------- fp32 -> bf16 convert ----------------
__global__ __launch_bounds__(256) void cvt_bf16(const float* __restrict__ in,
                                                __bf16* __restrict__ out, int n4) {
  int i = blockIdx.x * 256 + threadIdx.x;
  if (i >= n4) return;
  float4 v = ((const float4*)in)[i];
  bf16x4 o = {(__bf16)v.x, (__bf16)v.y, (__bf16)v.z, (__bf16)v.w};
  ((bf16x4*)out)[i] = o;
}

// ---------------- NT GEMM: C[M,N] = A[M,K] * B[N,K]^T ----------------
__global__ __launch_bounds__(256, 2)
void gemm_bt(const __bf16* __restrict__ A, const __bf16* __restrict__ B,
             float* __restrict__ Cf, __bf16* __restrict__ Cb,
             int M, int N, int K) {
  __shared__ __align__(16) __bf16 sA[16 * CH];
  __shared__ __align__(16) __bf16 sB[16 * CH];
  const int tid = threadIdx.x;
  const int wave = tid >> 6, lane = tid & 63;
  const int ntiles = N >> 7;
  const int bm = blockIdx.x / ntiles, bn = blockIdx.x % ntiles;
  const int wm = wave & 1, wn = wave >> 1;
  const int rowA0 = bm << 7, rowB0 = bn << 7;
  const int lr = lane >> 3;
  const int lc = (lane & 7) * 8;

  floatx4 acc[4][4] = {};

  for (int k0 = 0; k0 < K; k0 += 64) {
    __syncthreads();
    for (int j = 0; j < 4; ++j) {
      int c = wave * 4 + j;
      gl_lds16(A + (size_t)(rowA0 + c * 8 + lr) * K + k0 + lc, sA + c * CH);
      gl_lds16(B + (size_t)(rowB0 + c * 8 + lr) * K + k0 + lc, sB + c * CH);
    }
    __syncthreads();
    for (int kb = 0; kb < 64; kb += 32) {
      const int ko = kb + (lane >> 4) * 8;
      bf16x8 af[4], bfv[4];
      for (int t = 0; t < 4; ++t) {
        af[t]  = *(const bf16x8*)(sA + pidx(wm * 64 + t * 16 + (lane & 15), ko));
        bfv[t] = *(const bf16x8*)(sB + pidx(wn * 64 + t * 16 + (lane & 15), ko));
      }
      for (int mt = 0; mt < 4; ++mt)
        for (int nt = 0; nt < 4; ++nt)
          acc[mt][nt] = __builtin_amdgcn_mfma_f32_16x16x32_bf16(af[mt], bfv[nt],
                                                                acc[mt][nt], 0, 0, 0);
    }
  }
  for (int mt = 0; mt < 4; ++mt)
    for (int nt = 0; nt < 4; ++nt)
      for (int r = 0; r < 4; ++r) {
        int row = rowA0 + wm * 64 + mt * 16 + (lane >> 4) * 4 + r;
        int col = rowB0 + wn * 64 + nt * 16 + (lane & 15);
        if (Cf) Cf[(size_t)row * N + col] = acc[mt][nt][r];
        else    Cb[(size_t)row * N + col] = (__bf16)acc[mt][nt][r];
      }
}

// ---------------- qk-norm + RoPE2D (Q and K only) ----------------
__global__ __launch_bounds__(256)
void normrope(const __bf16* __restrict__ qkv, __bf16* __restrict__ Q,
              __bf16* __restrict__ K, const int* __restrict__ Wp) {
  const int unit = blockIdx.x * 4 + (threadIdx.x >> 6);
  const int lane = threadIdx.x & 63;
  const int row = unit / 20, hh = unit % 20;
  const int b = row >> 10, l = row & 1023;

  const __bf16* src = (hh < 16) ? qkv + (size_t)row * 1536 + hh * 64
                                : qkv + (size_t)row * 1536 + 1024 + (hh - 16) * 64;
  float t = (float)src[lane];

  float ss = t * t;
  for (int m = 1; m < 64; m <<= 1) ss += __shfl_xor(ss, m);
  t = t / (sqrtf(ss) + 1e-10f);

  const int W = Wp[0];
  const int ph = l / W, pw = l % W;
  const int i = lane & 31;
  float x1 = __shfl(t, 2 * i);
  float x2 = __shfl(t, 2 * i + 1);
  float invf = exp2f(-(float)i * 0.03125f * 13.287712379549449f);  // theta^(-i/32)
  float f = (float)(ph + pw) * invf;
  float c = cosf(f), s = sinf(f);
  t = (lane < 32) ? (x1 * c - x2 * s) : (x1 * s + x2 * c);

  if (hh < 16)
    Q[(((size_t)b * 16 + hh) * 1024 + l) * 64 + lane] = (__bf16)t;
  else
    K[(((size_t)b * 4 + (hh - 16)) * 1024 + l) * 64 + lane] = (__bf16)t;
}

// ---------------- V transpose: Vt[b][g][d][l] ----------------
// 64(l) x 64(d) tile per block; 256 threads handle 32 rows per pass ->
// TWO passes for load and for store (round-2 bug: only one pass loaded).
__global__ __launch_bounds__(256)
void vtrans(const __bf16* __restrict__ qkv, __bf16* __restrict__ Vt) {
  __shared__ __align__(16) __bf16 sT[64 * 72];
  const int bid = blockIdx.x;
  const int lt = bid & 15, g = (bid >> 4) & 3, b = bid >> 6;
  const int t = threadIdx.x;
  const int cc = (t & 7) * 8;

  for (int i = 0; i < 2; ++i) {
    int l = (t >> 3) + 32 * i;
    bf16x8 v = *(const bf16x8*)(qkv + ((size_t)(b * 1024 + lt * 64 + l)) * 1536 +
                                1280 + g * 64 + cc);
    *(bf16x8*)(sT + l * 72 + (cc ^ ((l & 7) * 8))) = v;
  }
  __syncthreads();

  for (int i = 0; i < 2; ++i) {
    int d = (t >> 3) + 32 * i;
    int lc = (t & 7) * 8;
    bf16x8 o;
    for (int j = 0; j < 8; ++j) {
      int rrow = lc + j;
      o[j] = sT[rrow * 72 + (d ^ ((rrow & 7) * 8))];
    }
    *(bf16x8*)(Vt + (((size_t)(b * 4 + g) * 64) + d) * 1024 + lt * 64 + lc) = o;
  }
}

// ---------------- flash attention (fixed-max softmax) ----------------
// scores*scale in [-0.125,0.125] since q,k unit vectors => no online max.
// BLOCK_M=128, BLOCK_N=64, D=64; 4 waves x 32 q-rows.
__global__ __launch_bounds__(256, 4)
void flash(const __bf16* __restrict__ Q, const __bf16* __restrict__ K,
           const __bf16* __restrict__ Vt, __bf16* __restrict__ Oout) {
  __shared__ __align__(16) __bf16 sK[8 * CH];
  __shared__ __align__(16) __bf16 sV[8 * CH];      // [dim][key], chunk-padded
  __shared__ __align__(16) __bf16 sQP[128 * 72];   // sQ (plain) then sP (stride 72)
  const int tid = threadIdx.x, wave = tid >> 6, lane = tid & 63;
  const int quad = lane >> 4, lm = lane & 15;
  const int bid = blockIdx.x;
  const int qt = bid & 7, h = (bid >> 3) & 15, b = bid >> 7;
  const int g = h >> 2;
  const __bf16* Qb = Q + (((size_t)b * 16 + h) * 1024 + qt * 128) * 64;
  const __bf16* Kb = K + ((size_t)b * 4 + g) * 1024 * 64;
  const __bf16* Vb = Vt + ((size_t)b * 4 + g) * 64 * 1024;

  // stage Q tile (contiguous, plain layout), then hoist fragments to regs
  for (int j = 0; j < 4; ++j) {
    int c = wave * 4 + j;
    gl_lds16(Qb + c * 512 + lane * 8, sQP + c * 512);
  }
  __syncthreads();
  bf16x8 qf[2][2];
  for (int mt = 0; mt < 2; ++mt)
    for (int hh = 0; hh < 2; ++hh)
      qf[mt][hh] = *(const bf16x8*)(sQP + (wave * 32 + mt * 16 + lm) * 64 +
                                    hh * 32 + quad * 8);

  float l_i[2][4] = {};
  floatx4 accO[2][4] = {};
  const float C = 0.18033688011112042f;  // (1/8) * log2(e)

  for (int kt = 0; kt < 16; ++kt) {
    __syncthreads();  // prev-iter sK/sV reads done; (kt==0) qf reads done
    if (wave < 2) {
      for (int j = 0; j < 4; ++j) {
        int c = wave * 4 + j;
        gl_lds16(Kb + (size_t)kt * 4096 + c * 512 + lane * 8, sK + c * CH);
      }
    } else {
      for (int j = 0; j < 4; ++j) {
        int c = (wave - 2) * 4 + j;
        gl_lds16(Vb + (size_t)(c * 8 + (lane >> 3)) * 1024 + kt * 64 + (lane & 7) * 8,
                 sV + c * CH);
      }
    }
    __syncthreads();  // staging complete

    // S = Q K^T
    floatx4 accS[2][4] = {};
    for (int hh = 0; hh < 2; ++hh) {
      const int ko = hh * 32 + quad * 8;
      bf16x8 kf[4];
      for (int nt = 0; nt < 4; ++nt)
        kf[nt] = *(const bf16x8*)(sK + pidx(nt * 16 + lm, ko));
      for (int mt = 0; mt < 2; ++mt)
        for (int nt = 0; nt < 4; ++nt)
          accS[mt][nt] = __builtin_amdgcn_mfma_f32_16x16x32_bf16(qf[mt][hh], kf[nt],
                                                                 accS[mt][nt], 0, 0, 0);
    }

    // p = exp2(s*C); per-lane partial row sums; stage P (own rows only)
    for (int mt = 0; mt < 2; ++mt)
      for (int nt = 0; nt < 4; ++nt)
        for (int r = 0; r < 4; ++r) {
          float p = __builtin_amdgcn_exp2f(accS[mt][nt][r] * C);
          l_i[mt][r] += p;
          sQP[(wave * 32 + mt * 16 + quad * 4 + r) * 72 + nt * 16 + lm] = (__bf16)p;
        }

    // O += P V  (within-wave sP dependency; no barrier needed)
    for (int hh = 0; hh < 2; ++hh) {
      const int ko = hh * 32 + quad * 8;
      bf16x8 pf[2], vf[4];
      for (int mt = 0; mt < 2; ++mt)
        pf[mt] = *(const bf16x8*)(sQP + (wave * 32 + mt * 16 + lm) * 72 + ko);
      for (int nt = 0; nt < 4; ++nt)
        vf[nt] = *(const bf16x8*)(sV + pidx(nt * 16 + lm, ko));
      for (int mt = 0; mt < 2; ++mt)
        for (int nt = 0; nt < 4; ++nt)
          accO[mt][nt] = __builtin_amdgcn_mfma_f32_16x16x32_bf16(pf[mt], vf[nt],
                                                                 accO[mt][nt], 0, 0, 0);
    }
  }

  // reduce row sums across the 16 lanes holding the row's columns
  for (int mt = 0; mt < 2; ++mt)
    for (int r = 0; r < 4; ++r) {
      float l = l_i[mt][r];
      for (int m = 1; m < 16; m <<= 1) l += __shfl_xor(l, m);
      l_i[mt][r] = 1.f / l;
    }

  for (int mt = 0; mt < 2; ++mt)
    for (int r = 0; r < 4; ++r) {
      int row = qt * 128 + wave * 32 + mt * 16 + quad * 4 + r;
      for (int nt = 0; nt < 4; ++nt) {
        int col = nt * 16 + lm;
        Oout[((size_t)b * 1024 + row) * 1024 + h * 64 + col] =
            (__bf16)(accO[mt][nt][r] * l_i[mt][r]);
      }
    }
}

extern "C" void kernel_launch(void* const* d_in, const int* in_sizes, int n_in,
                              void* d_out, int out_size, void* d_ws, size_t ws_size,
                              hipStream_t stream) {
  const float* x     = (const float*)d_in[0];
  const float* w_qkv = (const float*)d_in[1];
  const float* w_o   = (const float*)d_in[2];
  const int*   Wp    = (const int*)d_in[4];
  float* out = (float*)d_out;
  char* ws = (char*)d_ws;

  __bf16* xb    = (__bf16*)(ws + 0);          // 16 MiB
  __bf16* attn  = (__bf16*)(ws + 0);          // alias (xb dead after gemm1)
  __bf16* wqkvb = (__bf16*)(ws + 16777216);   // 3 MiB
  __bf16* wob   = (__bf16*)(ws + 19922944);   // 2 MiB
  __bf16* qkvb  = (__bf16*)(ws + 22020096);   // 24 MiB
  __bf16* Qb    = (__bf16*)(ws + 47185920);   // 16 MiB
  __bf16* Kb    = (__bf16*)(ws + 63963136);   // 4 MiB
  __bf16* Vtb   = (__bf16*)(ws + 68157440);   // 4 MiB

  cvt_bf16<<<8192, 256, 0, stream>>>(x, xb, 2097152);
  cvt_bf16<<<1536, 256, 0, stream>>>(w_qkv, wqkvb, 393216);
  cvt_bf16<<<1024, 256, 0, stream>>>(w_o, wob, 262144);

  gemm_bt<<<64 * 12, 256, 0, stream>>>(xb, wqkvb, nullptr, qkvb, 8192, 1536, 1024);

  normrope<<<40960, 256, 0, stream>>>(qkvb, Qb, Kb, Wp);
  vtrans<<<512, 256, 0, stream>>>(qkvb, Vtb);

  flash<<<1024, 256, 0, stream>>>(Qb, Kb, Vtb, attn);

  gemm_bt<<<64 * 8, 256, 0, stream>>>(attn, wob, out, nullptr, 8192, 1024, 1024);
}

// Round 4
// 253.025 us; speedup vs baseline: 1.3224x; 1.0858x over previous
//
#include <hip/hip_runtime.h>
#include <hip/hip_bf16.h>
#include <cstdint>
#include <cstddef>

// B=8, L=1024, D=1024, NUM_HEADS=16, QUERY_GROUPS=4, HEAD_DIM=64, QKV_OUT=1536

typedef __bf16 bf16x8 __attribute__((ext_vector_type(8)));
typedef __bf16 bf16x4 __attribute__((ext_vector_type(4)));
typedef float floatx4 __attribute__((ext_vector_type(4)));
typedef uint32_t u32x2 __attribute__((ext_vector_type(2)));
typedef uint32_t u32x4 __attribute__((ext_vector_type(4)));

typedef unsigned int u32_g __attribute__((address_space(1)));
typedef unsigned int u32_l __attribute__((address_space(3)));

__device__ __forceinline__ void gl_lds16(const void* g, void* l) {
  __builtin_amdgcn_global_load_lds((const u32_g*)g, (u32_l*)l, 16, 0, 0);
}

// chunk-padded LDS staging for GEMM: 1024B chunk (8 rows x 64 bf16) + 16B pad.
constexpr int CH = 520;
__device__ __forceinline__ int pidx(int r, int k) {
  return (r >> 3) * CH + (r & 7) * 64 + k;
}

// ---------------- fp32 -> bf16 convert ----------------
__global__ __launch_bounds__(256) void cvt_bf16(const float* __restrict__ in,
                                                __bf16* __restrict__ out, int n4) {
  int i = blockIdx.x * 256 + threadIdx.x;
  if (i >= n4) return;
  float4 v = ((const float4*)in)[i];
  bf16x4 o = {(__bf16)v.x, (__bf16)v.y, (__bf16)v.z, (__bf16)v.w};
  ((bf16x4*)out)[i] = o;
}

// ---------------- NT GEMM: C[M,N] = A[M,K] * B[N,K]^T ----------------
__global__ __launch_bounds__(256, 2)
void gemm_bt(const __bf16* __restrict__ A, const __bf16* __restrict__ B,
             float* __restrict__ Cf, __bf16* __restrict__ Cb,
             int M, int N, int K) {
  __shared__ __align__(16) __bf16 sA[16 * CH];
  __shared__ __align__(16) __bf16 sB[16 * CH];
  const int tid = threadIdx.x;
  const int wave = tid >> 6, lane = tid & 63;
  const int ntiles = N >> 7;
  const int bm = blockIdx.x / ntiles, bn = blockIdx.x % ntiles;
  const int wm = wave & 1, wn = wave >> 1;
  const int rowA0 = bm << 7, rowB0 = bn << 7;
  const int lr = lane >> 3;
  const int lc = (lane & 7) * 8;

  floatx4 acc[4][4] = {};

  for (int k0 = 0; k0 < K; k0 += 64) {
    __syncthreads();
    for (int j = 0; j < 4; ++j) {
      int c = wave * 4 + j;
      gl_lds16(A + (size_t)(rowA0 + c * 8 + lr) * K + k0 + lc, sA + c * CH);
      gl_lds16(B + (size_t)(rowB0 + c * 8 + lr) * K + k0 + lc, sB + c * CH);
    }
    __syncthreads();
    for (int kb = 0; kb < 64; kb += 32) {
      const int ko = kb + (lane >> 4) * 8;
      bf16x8 af[4], bfv[4];
      for (int t = 0; t < 4; ++t) {
        af[t]  = *(const bf16x8*)(sA + pidx(wm * 64 + t * 16 + (lane & 15), ko));
        bfv[t] = *(const bf16x8*)(sB + pidx(wn * 64 + t * 16 + (lane & 15), ko));
      }
      for (int mt = 0; mt < 4; ++mt)
        for (int nt = 0; nt < 4; ++nt)
          acc[mt][nt] = __builtin_amdgcn_mfma_f32_16x16x32_bf16(af[mt], bfv[nt],
                                                                acc[mt][nt], 0, 0, 0);
    }
  }
  for (int mt = 0; mt < 4; ++mt)
    for (int nt = 0; nt < 4; ++nt)
      for (int r = 0; r < 4; ++r) {
        int row = rowA0 + wm * 64 + mt * 16 + (lane >> 4) * 4 + r;
        int col = rowB0 + wn * 64 + nt * 16 + (lane & 15);
        if (Cf) Cf[(size_t)row * N + col] = acc[mt][nt][r];
        else    Cb[(size_t)row * N + col] = (__bf16)acc[mt][nt][r];
      }
}

// ---------------- qk-norm + RoPE2D (Q and K only) ----------------
// Q additionally pre-scaled by 1/8 (= 1/sqrt(HEAD_DIM)) so flash's QK^T
// accumulators are already the softmax exponent argument.
__global__ __launch_bounds__(256)
void normrope(const __bf16* __restrict__ qkv, __bf16* __restrict__ Q,
              __bf16* __restrict__ K, const int* __restrict__ Wp) {
  const int unit = blockIdx.x * 4 + (threadIdx.x >> 6);
  const int lane = threadIdx.x & 63;
  const int row = unit / 20, hh = unit % 20;
  const int b = row >> 10, l = row & 1023;

  const __bf16* src = (hh < 16) ? qkv + (size_t)row * 1536 + hh * 64
                                : qkv + (size_t)row * 1536 + 1024 + (hh - 16) * 64;
  float t = (float)src[lane];

  float ss = t * t;
  for (int m = 1; m < 64; m <<= 1) ss += __shfl_xor(ss, m);
  t = t / (sqrtf(ss) + 1e-10f);

  const int W = Wp[0];
  const int ph = l / W, pw = l % W;
  const int i = lane & 31;
  float x1 = __shfl(t, 2 * i);
  float x2 = __shfl(t, 2 * i + 1);
  float invf = exp2f(-(float)i * 0.03125f * 13.287712379549449f);  // theta^(-i/32)
  float f = (float)(ph + pw) * invf;
  float c = cosf(f), s = sinf(f);
  t = (lane < 32) ? (x1 * c - x2 * s) : (x1 * s + x2 * c);

  if (hh < 16)
    Q[(((size_t)b * 16 + hh) * 1024 + l) * 64 + lane] = (__bf16)(t * 0.125f);
  else
    K[(((size_t)b * 4 + (hh - 16)) * 1024 + l) * 64 + lane] = (__bf16)t;
}

// ---------------- V transpose: Vt[b][g][d][l] ----------------
__global__ __launch_bounds__(256)
void vtrans(const __bf16* __restrict__ qkv, __bf16* __restrict__ Vt) {
  __shared__ __align__(16) __bf16 sT[64 * 72];
  const int bid = blockIdx.x;
  const int lt = bid & 15, g = (bid >> 4) & 3, b = bid >> 6;
  const int t = threadIdx.x;
  const int cc = (t & 7) * 8;

  for (int i = 0; i < 2; ++i) {
    int l = (t >> 3) + 32 * i;
    bf16x8 v = *(const bf16x8*)(qkv + ((size_t)(b * 1024 + lt * 64 + l)) * 1536 +
                                1280 + g * 64 + cc);
    *(bf16x8*)(sT + l * 72 + (cc ^ ((l & 7) * 8))) = v;
  }
  __syncthreads();

  for (int i = 0; i < 2; ++i) {
    int d = (t >> 3) + 32 * i;
    int lc = (t & 7) * 8;
    bf16x8 o;
    for (int j = 0; j < 8; ++j) {
      int rrow = lc + j;
      o[j] = sT[rrow * 72 + (d ^ ((rrow & 7) * 8))];
    }
    *(bf16x8*)(Vt + (((size_t)(b * 4 + g) * 64) + d) * 1024 + lt * 64 + lc) = o;
  }
}

// ---------------- flash attention, S^T formulation ----------------
// S^T = K*Q^T puts q-row at lane&15 and key at quad*4+reg. A global key
// permutation kappa(k) = (2*(k>>5)+((k>>3... (see pf/vf indexing) makes the
// PV A-fragment exactly the lane-local exp'd accumulators: NO LDS for P.
// LDS: sK 8KB + sV 8KB (Q staged through the union once). XOR-granule
// swizzled staging -> conflict-free b128/b64 reads.
__global__ __launch_bounds__(256, 4)
void flash(const __bf16* __restrict__ Q, const __bf16* __restrict__ K,
           const __bf16* __restrict__ Vt, __bf16* __restrict__ Oout) {
  __shared__ __align__(16) __bf16 sKV[8192];  // [0,4096): K, [4096,8192): V
  __shared__ float sL[128];
  const int tid = threadIdx.x, wave = tid >> 6, lane = tid & 63;
  const int quad = lane >> 4, lm = lane & 15;
  const int qt = blockIdx.x & 7, h = (blockIdx.x >> 3) & 15, b = blockIdx.x >> 7;
  const int g = h >> 2;
  const __bf16* Qb = Q + (((size_t)b * 16 + h) * 1024 + qt * 128) * 64;
  const __bf16* Kb = K + ((size_t)b * 4 + g) * 1024 * 64;
  const __bf16* Vb = Vt + ((size_t)b * 4 + g) * 64 * 1024;

  // staging swizzle: physical slot i holds row i>>3, granule (i&7)^(i>>3)
  const int r8 = lane >> 3, gsw = (lane & 7) ^ r8;

  // stage Q (128 rows x 64) through the whole 16KB buffer, hoist frags
  for (int j = 0; j < 4; ++j) {
    int c = wave * 4 + j;
    gl_lds16(Qb + (size_t)(c * 8 + r8) * 64 + gsw * 8, sKV + c * 512);
  }
  __syncthreads();
  bf16x8 qf[2][2];
  for (int mt = 0; mt < 2; ++mt)
    for (int hh = 0; hh < 2; ++hh) {
      int r = wave * 32 + mt * 16 + lm;
      qf[mt][hh] = *(const bf16x8*)(sKV + (r >> 3) * 512 + (r & 7) * 64 +
                                    (((hh * 4 + quad) ^ (r & 7)) * 8));
    }

  float l_acc[2] = {0.f, 0.f};
  floatx4 accO[2][4] = {};

  for (int kt = 0; kt < 16; ++kt) {
    __syncthreads();  // prev compute's LDS reads (and qf hoist) done
    if (wave < 2) {
      for (int j = 0; j < 4; ++j) {
        int c = wave * 4 + j;
        gl_lds16(Kb + (size_t)(kt * 64 + c * 8 + r8) * 64 + gsw * 8, sKV + c * 512);
      }
    } else {
      for (int j = 0; j < 4; ++j) {
        int c = (wave - 2) * 4 + j;
        gl_lds16(Vb + (size_t)(c * 8 + r8) * 1024 + kt * 64 + gsw * 8,
                 sKV + 4096 + c * 512);
      }
    }
    __syncthreads();

    // S^T tiles: accT[nt][mt], key = nt*16 + quad*4 + reg, q-row = mt*16 + lm
    floatx4 accT[4][2] = {};
    for (int hh = 0; hh < 2; ++hh) {
      bf16x8 kf[4];
      for (int nt = 0; nt < 4; ++nt) {
        int r = nt * 16 + lm;
        kf[nt] = *(const bf16x8*)(sKV + (r >> 3) * 512 + (r & 7) * 64 +
                                  (((hh * 4 + quad) ^ (r & 7)) * 8));
      }
      for (int nt = 0; nt < 4; ++nt)
        for (int mt = 0; mt < 2; ++mt)
          accT[nt][mt] = __builtin_amdgcn_mfma_f32_16x16x32_bf16(
              kf[nt], qf[mt][hh], accT[nt][mt], 0, 0, 0);
    }

    // p = exp(y), y = s/8 (Q pre-scaled), |y|<=0.13: 2-term poly suffices
    // (rel err <= 3.3e-4 << bf16 quantization of P).
    // pf[hh][mt] element j <- accT[2*hh + (j>>2)][mt] reg (j&3): lane-local!
    bf16x8 pf[2][2];
    for (int nt = 0; nt < 4; ++nt)
      for (int mt = 0; mt < 2; ++mt)
        for (int r = 0; r < 4; ++r) {
          float y = accT[nt][mt][r];
          float p = fmaf(y, fmaf(y, 0.5f, 1.0f), 1.0f);
          l_acc[mt] += p;
          pf[nt >> 1][mt][(nt & 1) * 4 + r] = (__bf16)p;
        }

    // O += P*V with key order kappa: B-frag lane (quad,d) reads sV cols
    // (2hh)*16+quad*4.. and (2hh+1)*16+quad*4.. (two b64 reads)
    for (int hh = 0; hh < 2; ++hh)
      for (int dt = 0; dt < 4; ++dt) {
        int r = dt * 16 + lm;
        int rowoff = 4096 + (r >> 3) * 512 + (r & 7) * 64;
        int lgA = hh * 4 + (quad >> 1);
        u32x2 vA = *(const u32x2*)(sKV + rowoff + ((lgA ^ (r & 7)) * 8) + (quad & 1) * 4);
        u32x2 vB = *(const u32x2*)(sKV + rowoff + (((lgA + 2) ^ (r & 7)) * 8) + (quad & 1) * 4);
        u32x4 vw = {vA[0], vA[1], vB[0], vB[1]};
        bf16x8 vf = __builtin_bit_cast(bf16x8, vw);
        for (int mt = 0; mt < 2; ++mt)
          accO[mt][dt] = __builtin_amdgcn_mfma_f32_16x16x32_bf16(
              pf[hh][mt], vf, accO[mt][dt], 0, 0, 0);
      }
  }

  // row sums: lane (quad,lm) holds partials of row mt*16+lm; reduce quads
  for (int mt = 0; mt < 2; ++mt) {
    float l = l_acc[mt];
    l += __shfl_xor(l, 16);
    l += __shfl_xor(l, 32);
    if (quad == 0) sL[wave * 32 + mt * 16 + lm] = l;
  }
  __syncthreads();

  // accO C-layout: row = mt*16 + quad*4 + r, col(dim) = dt*16 + lm
  for (int mt = 0; mt < 2; ++mt)
    for (int r = 0; r < 4; ++r) {
      float inv = 1.f / sL[wave * 32 + mt * 16 + quad * 4 + r];
      int row = qt * 128 + wave * 32 + mt * 16 + quad * 4 + r;
      for (int dt = 0; dt < 4; ++dt) {
        int col = dt * 16 + lm;
        Oout[((size_t)b * 1024 + row) * 1024 + h * 64 + col] =
            (__bf16)(accO[mt][dt][r] * inv);
      }
    }
}

extern "C" void kernel_launch(void* const* d_in, const int* in_sizes, int n_in,
                              void* d_out, int out_size, void* d_ws, size_t ws_size,
                              hipStream_t stream) {
  const float* x     = (const float*)d_in[0];
  const float* w_qkv = (const float*)d_in[1];
  const float* w_o   = (const float*)d_in[2];
  const int*   Wp    = (const int*)d_in[4];
  float* out = (float*)d_out;
  char* ws = (char*)d_ws;

  __bf16* xb    = (__bf16*)(ws + 0);          // 16 MiB
  __bf16* attn  = (__bf16*)(ws + 0);          // alias (xb dead after gemm1)
  __bf16* wqkvb = (__bf16*)(ws + 16777216);   // 3 MiB
  __bf16* wob   = (__bf16*)(ws + 19922944);   // 2 MiB
  __bf16* qkvb  = (__bf16*)(ws + 22020096);   // 24 MiB
  __bf16* Qb    = (__bf16*)(ws + 47185920);   // 16 MiB
  __bf16* Kb    = (__bf16*)(ws + 63963136);   // 4 MiB
  __bf16* Vtb   = (__bf16*)(ws + 68157440);   // 4 MiB

  cvt_bf16<<<8192, 256, 0, stream>>>(x, xb, 2097152);
  cvt_bf16<<<1536, 256, 0, stream>>>(w_qkv, wqkvb, 393216);
  cvt_bf16<<<1024, 256, 0, stream>>>(w_o, wob, 262144);

  gemm_bt<<<64 * 12, 256, 0, stream>>>(xb, wqkvb, nullptr, qkvb, 8192, 1536, 1024);

  normrope<<<40960, 256, 0, stream>>>(qkvb, Qb, Kb, Wp);
  vtrans<<<512, 256, 0, stream>>>(qkvb, Vtb);

  flash<<<1024, 256, 0, stream>>>(Qb, Kb, Vtb, attn);

  gemm_bt<<<64 * 8, 256, 0, stream>>>(attn, wob, out, nullptr, 8192, 1024, 1024);
}

// Round 5
// 213.449 us; speedup vs baseline: 1.5676x; 1.1854x over previous
//
#include <hip/hip_runtime.h>
#include <hip/hip_bf16.h>
#include <cstdint>
#include <cstddef>

// B=8, L=1024, D=1024, NUM_HEADS=16, QUERY_GROUPS=4, HEAD_DIM=64, QKV_OUT=1536

typedef __bf16 bf16x8 __attribute__((ext_vector_type(8)));
typedef __bf16 bf16x4 __attribute__((ext_vector_type(4)));
typedef float floatx4 __attribute__((ext_vector_type(4)));
typedef uint32_t u32x2 __attribute__((ext_vector_type(2)));
typedef uint32_t u32x4 __attribute__((ext_vector_type(4)));

typedef unsigned int u32_g __attribute__((address_space(1)));
typedef unsigned int u32_l __attribute__((address_space(3)));

__device__ __forceinline__ void gl_lds16(const void* g, void* l) {
  __builtin_amdgcn_global_load_lds((const u32_g*)g, (u32_l*)l, 16, 0, 0);
}

// chunk-padded LDS staging for GEMM: 1024B chunk (8 rows x 64 bf16) + 16B pad.
constexpr int CH = 520;
__device__ __forceinline__ int pidx(int r, int k) {
  return (r >> 3) * CH + (r & 7) * 64 + k;
}

#define LOG2_THETA 13.287712379549449f  // log2(10000)

// ---------------- fused fp32 -> bf16 convert (x | w_qkv | w_o) ----------------
// bf16 outputs are laid out contiguously in ws, so one output pointer.
__global__ __launch_bounds__(256)
void cvt_all(const float* __restrict__ x, const float* __restrict__ wq,
             const float* __restrict__ wo, __bf16* __restrict__ out) {
  int i = blockIdx.x * 256 + threadIdx.x;  // grid covers exactly 2752512
  float4 v;
  if (i < 2097152)      v = ((const float4*)x)[i];
  else if (i < 2490368) v = ((const float4*)wq)[i - 2097152];
  else                  v = ((const float4*)wo)[i - 2490368];
  bf16x4 o = {(__bf16)v.x, (__bf16)v.y, (__bf16)v.z, (__bf16)v.w};
  ((bf16x4*)out)[i] = o;
}

// ---------------- GEMM1 fused: qkv proj + qk-norm + RoPE2D + V transpose ----
// C[8192,1536] = A[8192,1024] * B[1536,1024]^T, never materialized:
// each wave's 64x64 tile is one head-chunk x 64 rows; epilogue emits
// Q[b][h][l][d] (normed+roped+/8), K[b][g][l][d] (normed+roped),
// Vt[b][g][d][l] (LDS-transposed).
__global__ __launch_bounds__(256, 2)
void gemm_qkv(const __bf16* __restrict__ A, const __bf16* __restrict__ Bw,
              __bf16* __restrict__ Q, __bf16* __restrict__ Ko,
              __bf16* __restrict__ Vt, const int* __restrict__ Wp) {
  __shared__ __align__(16) __bf16 sAB[32 * CH];
  __bf16* sA = sAB;
  __bf16* sB = sAB + 16 * CH;
  const int tid = threadIdx.x, wave = tid >> 6, lane = tid & 63;
  const int quad = lane >> 4, lm = lane & 15;
  const int bm = blockIdx.x / 12, bn = blockIdx.x % 12;
  const int wm = wave & 1, wn = wave >> 1;
  const int rowA0 = bm << 7, rowB0 = bn << 7;
  const int lr = lane >> 3, lc = (lane & 7) * 8;

  floatx4 acc[4][4] = {};

  for (int k0 = 0; k0 < 1024; k0 += 64) {
    __syncthreads();
    for (int j = 0; j < 4; ++j) {
      int c = wave * 4 + j;
      gl_lds16(A + (size_t)(rowA0 + c * 8 + lr) * 1024 + k0 + lc, sA + c * CH);
      gl_lds16(Bw + (size_t)(rowB0 + c * 8 + lr) * 1024 + k0 + lc, sB + c * CH);
    }
    __syncthreads();
    for (int kb = 0; kb < 64; kb += 32) {
      const int ko = kb + quad * 8;
      bf16x8 af[4], bfv[4];
      for (int t = 0; t < 4; ++t) {
        af[t]  = *(const bf16x8*)(sA + pidx(wm * 64 + t * 16 + lm, ko));
        bfv[t] = *(const bf16x8*)(sB + pidx(wn * 64 + t * 16 + lm, ko));
      }
      for (int mt = 0; mt < 4; ++mt)
        for (int nt = 0; nt < 4; ++nt)
          acc[mt][nt] = __builtin_amdgcn_mfma_f32_16x16x32_bf16(af[mt], bfv[nt],
                                                                acc[mt][nt], 0, 0, 0);
    }
  }

  __syncthreads();  // all waves' MFMA LDS reads done before sT reuse

  const int hc = bn * 2 + wn;       // head-chunk 0..23
  const int row0 = rowA0 + wm * 64; // this wave's first global row
  const int bb = row0 >> 10, l0 = row0 & 1023;

  if (hc < 20) {
    // ---- q/k: row-norm + RoPE, all in registers + shuffles ----
    const bool isq = hc < 16;
    const int W = Wp[0];
    const float invfA = exp2f(-(float)lm * 0.03125f * LOG2_THETA);
    const float invfB = exp2f(-(float)(lm + 16) * 0.03125f * LOG2_THETA);
    __bf16* base = isq
        ? Q + (((size_t)bb * 16 + hc) * 1024 + l0) * 64
        : Ko + (((size_t)bb * 4 + (hc - 16)) * 1024 + l0) * 64;
    const int srcA = (lane & 48) | ((2 * lm) & 15);  // quad*16 + (2i)&15
    const bool lo = lm < 8;
    for (int mt = 0; mt < 4; ++mt)
      for (int r = 0; r < 4; ++r) {
        float a0 = acc[mt][0][r], a1 = acc[mt][1][r];
        float a2 = acc[mt][2][r], a3 = acc[mt][3][r];
        float ss = a0 * a0 + a1 * a1 + a2 * a2 + a3 * a3;
        ss += __shfl_xor(ss, 1); ss += __shfl_xor(ss, 2);
        ss += __shfl_xor(ss, 4); ss += __shfl_xor(ss, 8);
        float rn = (isq ? 0.125f : 1.0f) / (sqrtf(ss) + 1e-10f);
        a0 *= rn; a1 *= rn; a2 *= rn; a3 *= rn;
        // pair A (out cols lm, 32+lm; i=lm): x1=in[2lm], x2=in[2lm+1]
        float e0 = __shfl(a0, srcA),     e1 = __shfl(a1, srcA);
        float f0 = __shfl(a0, srcA + 1), f1 = __shfl(a1, srcA + 1);
        // pair B (out cols 16+lm, 48+lm; i=16+lm): sources in cols 32+2lm
        float g0 = __shfl(a2, srcA),     g1 = __shfl(a3, srcA);
        float h0 = __shfl(a2, srcA + 1), h1 = __shfl(a3, srcA + 1);
        float x1A = lo ? e0 : e1, x2A = lo ? f0 : f1;
        float x1B = lo ? g0 : g1, x2B = lo ? h0 : h1;
        int lrow = l0 + mt * 16 + quad * 4 + r;
        int pos = lrow / W + lrow % W;
        float fA = (float)pos * invfA, fB = (float)pos * invfB;
        float cA = __cosf(fA), sA_ = __sinf(fA);
        float cB = __cosf(fB), sB_ = __sinf(fB);
        __bf16* dst = base + (size_t)(mt * 16 + quad * 4 + r) * 64;
        dst[lm]      = (__bf16)(x1A * cA - x2A * sA_);
        dst[lm + 16] = (__bf16)(x1B * cB - x2B * sB_);
        dst[lm + 32] = (__bf16)(x1A * sA_ + x2A * cA);
        dst[lm + 48] = (__bf16)(x1B * sB_ + x2B * cB);
      }
  } else {
    // ---- v: transpose 64x64 tile through wave-private LDS region ----
    const int g = hc - 20;
    __bf16* sT = sAB + wave * 4160;  // 64 rows x 65 cols, 4x4160 <= 32*CH
    for (int mt = 0; mt < 4; ++mt)
      for (int nt = 0; nt < 4; ++nt)
        for (int r = 0; r < 4; ++r)
          sT[(mt * 16 + quad * 4 + r) * 65 + nt * 16 + lm] =
              (__bf16)acc[mt][nt][r];
    // wave-local LDS RAW: compiler emits lgkmcnt wait
    for (int pp = 0; pp < 8; ++pp) {
      int d = pp * 8 + (lane >> 3);
      int lloc = (lane & 7) * 8;
      bf16x8 o;
      for (int j = 0; j < 8; ++j) o[j] = sT[(lloc + j) * 65 + d];
      *(bf16x8*)(Vt + (((size_t)bb * 4 + g) * 64 + d) * 1024 + l0 + lloc) = o;
    }
  }
}

// ---------------- NT GEMM (out proj): C[M,N] fp32 = A[M,K] * B[N,K]^T -------
__global__ __launch_bounds__(256, 2)
void gemm_bt(const __bf16* __restrict__ A, const __bf16* __restrict__ B,
             float* __restrict__ Cf, int M, int N, int K) {
  __shared__ __align__(16) __bf16 sA[16 * CH];
  __shared__ __align__(16) __bf16 sB[16 * CH];
  const int tid = threadIdx.x;
  const int wave = tid >> 6, lane = tid & 63;
  const int ntiles = N >> 7;
  const int bm = blockIdx.x / ntiles, bn = blockIdx.x % ntiles;
  const int wm = wave & 1, wn = wave >> 1;
  const int rowA0 = bm << 7, rowB0 = bn << 7;
  const int lr = lane >> 3;
  const int lc = (lane & 7) * 8;

  floatx4 acc[4][4] = {};

  for (int k0 = 0; k0 < K; k0 += 64) {
    __syncthreads();
    for (int j = 0; j < 4; ++j) {
      int c = wave * 4 + j;
      gl_lds16(A + (size_t)(rowA0 + c * 8 + lr) * K + k0 + lc, sA + c * CH);
      gl_lds16(B + (size_t)(rowB0 + c * 8 + lr) * K + k0 + lc, sB + c * CH);
    }
    __syncthreads();
    for (int kb = 0; kb < 64; kb += 32) {
      const int ko = kb + (lane >> 4) * 8;
      bf16x8 af[4], bfv[4];
      for (int t = 0; t < 4; ++t) {
        af[t]  = *(const bf16x8*)(sA + pidx(wm * 64 + t * 16 + (lane & 15), ko));
        bfv[t] = *(const bf16x8*)(sB + pidx(wn * 64 + t * 16 + (lane & 15), ko));
      }
      for (int mt = 0; mt < 4; ++mt)
        for (int nt = 0; nt < 4; ++nt)
          acc[mt][nt] = __builtin_amdgcn_mfma_f32_16x16x32_bf16(af[mt], bfv[nt],
                                                                acc[mt][nt], 0, 0, 0);
    }
  }
  for (int mt = 0; mt < 4; ++mt)
    for (int nt = 0; nt < 4; ++nt)
      for (int r = 0; r < 4; ++r) {
        int row = rowA0 + wm * 64 + mt * 16 + (lane >> 4) * 4 + r;
        int col = rowB0 + wn * 64 + nt * 16 + (lane & 15);
        Cf[(size_t)row * N + col] = acc[mt][nt][r];
      }
}

// ---------------- flash attention, S^T formulation, BN=128 -------------------
// Two sequential 64-key halves per LDS stage: barrier count halves vs BN=64.
// S^T = K*Q^T: q-row = lane&15, key = quad*4+reg. Key permutation kappa makes
// the PV A-fragment the lane-local exp'd accumulators (no LDS for P).
__global__ __launch_bounds__(256, 4)
void flash(const __bf16* __restrict__ Q, const __bf16* __restrict__ K,
           const __bf16* __restrict__ Vt, __bf16* __restrict__ Oout) {
  __shared__ __align__(16) __bf16 sKV[16384];  // K:[0,8192) V:[8192,16384)
  __shared__ float sL[128];
  const int tid = threadIdx.x, wave = tid >> 6, lane = tid & 63;
  const int quad = lane >> 4, lm = lane & 15;
  const int qt = blockIdx.x & 7, h = (blockIdx.x >> 3) & 15, b = blockIdx.x >> 7;
  const int g = h >> 2;
  const __bf16* Qb = Q + (((size_t)b * 16 + h) * 1024 + qt * 128) * 64;
  const __bf16* Kb = K + ((size_t)b * 4 + g) * 1024 * 64;
  const __bf16* Vb = Vt + ((size_t)b * 4 + g) * 64 * 1024;

  const int r8 = lane >> 3, gsw = (lane & 7) ^ r8;

  // stage Q (128x64) through sKV[0,8192), hoist fragments
  for (int j = 0; j < 4; ++j) {
    int c = wave * 4 + j;
    gl_lds16(Qb + (size_t)(c * 8 + r8) * 64 + gsw * 8, sKV + c * 512);
  }
  __syncthreads();
  bf16x8 qf[2][2];
  for (int mt = 0; mt < 2; ++mt)
    for (int hh = 0; hh < 2; ++hh) {
      int r = wave * 32 + mt * 16 + lm;
      qf[mt][hh] = *(const bf16x8*)(sKV + (r >> 3) * 512 + (r & 7) * 64 +
                                    (((hh * 4 + quad) ^ (r & 7)) * 8));
    }

  float l_acc[2] = {0.f, 0.f};
  floatx4 accO[2][4] = {};

  for (int kt = 0; kt < 8; ++kt) {
    __syncthreads();  // prev compute's LDS reads (and qf hoist) done
    {
      int half = wave & 1;
      if (wave < 2) {  // K tile rows kt*128 + half*64 + 0..63
        for (int c = 0; c < 8; ++c)
          gl_lds16(Kb + (size_t)(kt * 128 + half * 64 + c * 8 + r8) * 64 + gsw * 8,
                   sKV + half * 4096 + c * 512);
      } else {         // V tile keys kt*128 + half*64 + 0..63, all 64 dims
        for (int c = 0; c < 8; ++c)
          gl_lds16(Vb + (size_t)(c * 8 + r8) * 1024 + kt * 128 + half * 64 + gsw * 8,
                   sKV + 8192 + half * 4096 + c * 512);
      }
    }
    __syncthreads();

    for (int half = 0; half < 2; ++half) {
      const __bf16* sK = sKV + half * 4096;
      const __bf16* sV = sKV + 8192 + half * 4096;

      // S^T: accT[nt][mt], key = nt*16 + quad*4 + reg, q-row = mt*16 + lm
      floatx4 accT[4][2] = {};
      for (int hh = 0; hh < 2; ++hh) {
        bf16x8 kf[4];
        for (int nt = 0; nt < 4; ++nt) {
          int r = nt * 16 + lm;
          kf[nt] = *(const bf16x8*)(sK + (r >> 3) * 512 + (r & 7) * 64 +
                                    (((hh * 4 + quad) ^ (r & 7)) * 8));
        }
        for (int nt = 0; nt < 4; ++nt)
          for (int mt = 0; mt < 2; ++mt)
            accT[nt][mt] = __builtin_amdgcn_mfma_f32_16x16x32_bf16(
                kf[nt], qf[mt][hh], accT[nt][mt], 0, 0, 0);
      }

      // p = exp(y), |y| <= 0.13 (q,k unit + Q pre-scaled): 2-term poly
      bf16x8 pf[2][2];
      for (int nt = 0; nt < 4; ++nt)
        for (int mt = 0; mt < 2; ++mt)
          for (int r = 0; r < 4; ++r) {
            float y = accT[nt][mt][r];
            float p = fmaf(y, fmaf(y, 0.5f, 1.0f), 1.0f);
            l_acc[mt] += p;
            pf[nt >> 1][mt][(nt & 1) * 4 + r] = (__bf16)p;
          }

      // O += P*V under kappa key order: B-frag = two b64 reads from sV
      for (int hh = 0; hh < 2; ++hh)
        for (int dt = 0; dt < 4; ++dt) {
          int r = dt * 16 + lm;
          int rowoff = (r >> 3) * 512 + (r & 7) * 64;
          int lgA = hh * 4 + (quad >> 1);
          u32x2 vA = *(const u32x2*)(sV + rowoff + ((lgA ^ (r & 7)) * 8) + (quad & 1) * 4);
          u32x2 vB = *(const u32x2*)(sV + rowoff + (((lgA + 2) ^ (r & 7)) * 8) + (quad & 1) * 4);
          u32x4 vw = {vA[0], vA[1], vB[0], vB[1]};
          bf16x8 vf = __builtin_bit_cast(bf16x8, vw);
          for (int mt = 0; mt < 2; ++mt)
            accO[mt][dt] = __builtin_amdgcn_mfma_f32_16x16x32_bf16(
                pf[hh][mt], vf, accO[mt][dt], 0, 0, 0);
        }
    }
  }

  // row sums: lane (quad,lm) holds partials of row mt*16+lm; reduce quads
  for (int mt = 0; mt < 2; ++mt) {
    float l = l_acc[mt];
    l += __shfl_xor(l, 16);
    l += __shfl_xor(l, 32);
    if (quad == 0) sL[wave * 32 + mt * 16 + lm] = l;
  }
  __syncthreads();

  // accO C-layout: row = mt*16 + quad*4 + r, col(dim) = dt*16 + lm
  for (int mt = 0; mt < 2; ++mt)
    for (int r = 0; r < 4; ++r) {
      float inv = 1.f / sL[wave * 32 + mt * 16 + quad * 4 + r];
      int row = qt * 128 + wave * 32 + mt * 16 + quad * 4 + r;
      for (int dt = 0; dt < 4; ++dt) {
        int col = dt * 16 + lm;
        Oout[((size_t)b * 1024 + row) * 1024 + h * 64 + col] =
            (__bf16)(accO[mt][dt][r] * inv);
      }
    }
}

extern "C" void kernel_launch(void* const* d_in, const int* in_sizes, int n_in,
                              void* d_out, int out_size, void* d_ws, size_t ws_size,
                              hipStream_t stream) {
  const float* x     = (const float*)d_in[0];
  const float* w_qkv = (const float*)d_in[1];
  const float* w_o   = (const float*)d_in[2];
  const int*   Wp    = (const int*)d_in[4];
  float* out = (float*)d_out;
  char* ws = (char*)d_ws;

  // bf16 conversions contiguous at ws base (cvt_all writes one stream):
  __bf16* xb    = (__bf16*)(ws + 0);          // 16 MiB
  __bf16* attn  = (__bf16*)(ws + 0);          // alias (xb dead after gemm_qkv)
  __bf16* wqkvb = (__bf16*)(ws + 16777216);   // 3 MiB
  __bf16* wob   = (__bf16*)(ws + 19922944);   // 2 MiB
  __bf16* Qb    = (__bf16*)(ws + 22020096);   // 16 MiB
  __bf16* Kb    = (__bf16*)(ws + 38797312);   // 4 MiB
  __bf16* Vtb   = (__bf16*)(ws + 42991616);   // 4 MiB (total ~45 MiB)

  cvt_all<<<10752, 256, 0, stream>>>(x, w_qkv, w_o, (__bf16*)ws);

  // qkv proj + norm + rope + V-transpose, writes Q/K/Vt directly
  gemm_qkv<<<64 * 12, 256, 0, stream>>>(xb, wqkvb, Qb, Kb, Vtb, Wp);

  // fused attention
  flash<<<1024, 256, 0, stream>>>(Qb, Kb, Vtb, attn);

  // out = attn @ w_o^T : M=8192 N=1024 K=1024 -> fp32 d_out
  gemm_bt<<<64 * 8, 256, 0, stream>>>(attn, wob, out, 8192, 1024, 1024);
}